// Round 16
// baseline (678.920 us; speedup 1.0000x reference)
//
#include <hip/hip_runtime.h>

// Species-routed expert Linear, R16: natural-order BM=256 blocks + in-block
// species sort. Reads linear, writes window-local (512 KB/block), B panels of
// all 4 species register-shared per K-step (fragments select via scalar
// guard) -> L2 B-traffic 512 MB total. <=19 MFMA fragments of 16 rows.
//   out[a] = rho[a] @ W[sym[a]] + b[sym[a]]   (NTA=65536, K=N=512, 4 species)

#define NTA   65536
#define DIM_O 512
#define NMAXD 512
#define NSPE  4
#define BM    256
#define NFR   19            // max fragments: 16 + 3
#define NSLOT (NFR * 16)    // 304
#define BK    64

typedef __attribute__((ext_vector_type(4))) float  f32x4;
typedef __attribute__((ext_vector_type(8))) short  bf16x8;

__device__ __forceinline__ short f2bf(float f) {
    unsigned u = __builtin_bit_cast(unsigned, f);
    u += 0x7FFFu + ((u >> 16) & 1u);
    return (short)(u >> 16);
}

__device__ __forceinline__ void bar_lds() {
    asm volatile("s_waitcnt lgkmcnt(0)" ::: "memory");
    __builtin_amdgcn_s_barrier();
    __builtin_amdgcn_sched_barrier(0);
}

// Pack W[s][k][n] (fp32) -> bf16 MFMA-B fragment layout (proven R1-R15).
__global__ void pack_w_kernel(const float* __restrict__ W, short* __restrict__ Wp) {
    int idx = blockIdx.x * 256 + threadIdx.x;
    int j  = idx & 7;
    int l  = (idx >> 3) & 63;
    int nb = (idx >> 9) & 31;
    int kb = (idx >> 14) & 15;
    int s  = idx >> 18;
    int k = kb * 32 + (l >> 4) * 8 + j;
    int n = nb * 16 + (l & 15);
    Wp[idx] = f2bf(W[((size_t)s * DIM_O + k) * NMAXD + n]);
}

// LDS A: 16B granule idx = c*NSLOT + (slot ^ c), c = k-chunk of 8 floats
// (0..7); slot = 16*frag + r, XOR stays within the 16-group. Read 2-way max.
__global__ __launch_bounds__(1024, 1)
void gemm_kernel(const float* __restrict__ rho,
                 const short* __restrict__ Wp,
                 const float* __restrict__ bias,
                 const int*  __restrict__ sym,
                 float* __restrict__ out)
{
    const int g    = blockIdx.x;          // 256 consecutive atoms
    const int tid  = threadIdx.x;
    const int lane = tid & 63;
    const int w    = tid >> 6;            // wave 0..15 owns cols [w*32, w*32+32)
    const int lrow = lane & 15;
    const int lgr  = lane >> 4;

    __shared__ int wcnt[4][NSPE];
    __shared__ int slotOf[BM];
    __shared__ int s2a[NSLOT];
    __shared__ int Fsh[4];                // F1, F2, F3, NF (fragment prefixes)
    __shared__ __align__(16) short Ab[2][8 * NSLOT * 8];   // 2 x 38 KB

    if (tid < NSLOT) s2a[tid] = -1;

    unsigned long long m0 = 0, m1 = 0, m2 = 0, m3 = 0;
    int myspe = 0;
    if (tid < BM) {                       // waves 0..3 sort their 64 atoms
        myspe = sym[g * BM + tid];
        m0 = __ballot(myspe == 0);
        m1 = __ballot(myspe == 1);
        m2 = __ballot(myspe == 2);
        m3 = __ballot(myspe == 3);
        if (lane == 0) {
            wcnt[w][0] = __popcll(m0); wcnt[w][1] = __popcll(m1);
            wcnt[w][2] = __popcll(m2); wcnt[w][3] = __popcll(m3);
        }
    }
    __syncthreads();
    if (tid < BM) {
        int tot[NSPE];
        #pragma unroll
        for (int sp = 0; sp < NSPE; ++sp)
            tot[sp] = wcnt[0][sp] + wcnt[1][sp] + wcnt[2][sp] + wcnt[3][sp];
        int F[NSPE + 1]; F[0] = 0;
        #pragma unroll
        for (int sp = 0; sp < NSPE; ++sp) F[sp + 1] = F[sp] + ((tot[sp] + 15) >> 4);
        int rank = 0;
        #pragma unroll
        for (int ww = 0; ww < 4; ++ww) if (ww < w) rank += wcnt[ww][myspe];
        const unsigned long long ms = (myspe == 0) ? m0 : (myspe == 1) ? m1
                                     : (myspe == 2) ? m2 : m3;
        rank += (int)__popcll(ms & ((1ull << lane) - 1ull));
        const int slot = F[myspe] * 16 + rank;
        slotOf[tid] = slot;
        s2a[slot] = tid;
        if (tid == 0) { Fsh[0] = F[1]; Fsh[1] = F[2]; Fsh[2] = F[3]; Fsh[3] = F[4]; }
    }
    __syncthreads();

    const int F1 = Fsh[0], F2 = Fsh[1], F3 = Fsh[2], NF = Fsh[3];

    // linear staging: 4 threads/row, each 16 consecutive floats (64 B);
    // 4 adjacent lanes cover 256 B contiguous of one row -> requests merge.
    const int srow = tid >> 2;            // 0..255 natural row
    const int sc   = tid & 3;
    const float* gsrc = rho + (size_t)(g * BM + srow) * DIM_O + sc * 16;
    const int slotR = slotOf[srow];
    const int c0 = sc * 2;

    f32x4 st[4];
    #define LOADST(kt)                                                      \
        { _Pragma("unroll")                                                 \
          for (int i = 0; i < 4; ++i)                                       \
              st[i] = *(const f32x4*)(gsrc + (kt) * BK + i * 4); }
    #define WRITEA(bb)                                                      \
        { bf16x8 p0, p1;                                                    \
          _Pragma("unroll")                                                 \
          for (int q = 0; q < 4; ++q) {                                     \
              p0[q] = f2bf(st[0][q]); p0[4 + q] = f2bf(st[1][q]);           \
              p1[q] = f2bf(st[2][q]); p1[4 + q] = f2bf(st[3][q]);           \
          }                                                                 \
          *(bf16x8*)&Ab[bb][((c0    ) * NSLOT + (slotR ^ (c0    ))) * 8] = p0; \
          *(bf16x8*)&Ab[bb][((c0 + 1) * NSLOT + (slotR ^ (c0 + 1))) * 8] = p1; }

    f32x4 acc[NFR][2];
    #pragma unroll
    for (int f = 0; f < NFR; ++f) { acc[f][0] = (f32x4)0.0f; acc[f][1] = (f32x4)0.0f; }

    LOADST(0);
    WRITEA(0);
    __syncthreads();

    for (int kt = 0; kt < 8; ++kt) {
        const int buf = kt & 1;
        if (kt < 7) LOADST(kt + 1);       // linear, rides until the convert

        #pragma unroll
        for (int ks = 0; ks < 2; ++ks) {
            // B granules of ALL 4 species for this (kt,ks), register-shared
            bf16x8 bAll[NSPE][2];
            #pragma unroll
            for (int ss = 0; ss < NSPE; ++ss)
                #pragma unroll
                for (int nf = 0; nf < 2; ++nf)
                    bAll[ss][nf] = *(const bf16x8*)
                        (Wp + ((size_t)((ss * 16 + kt * 2 + ks) * 32) + w * 2 + nf) * 512
                            + lane * 8);
            const int cA = ks * 4 + lgr;
            #pragma unroll
            for (int f = 0; f < NFR; ++f) {
                if (f < NF) {
                    const int sp_s = __builtin_amdgcn_readfirstlane(
                        (f >= F1) + (f >= F2) + (f >= F3));
                    const bf16x8 af = *(const bf16x8*)
                        &Ab[buf][(cA * NSLOT + ((16 * f + lrow) ^ cA)) * 8];
                    #pragma unroll
                    for (int ss = 0; ss < NSPE; ++ss) {
                        if (ss == sp_s) {     // scalar branch, one taken
                            acc[f][0] = __builtin_amdgcn_mfma_f32_16x16x32_bf16(
                                af, bAll[ss][0], acc[f][0], 0, 0, 0);
                            acc[f][1] = __builtin_amdgcn_mfma_f32_16x16x32_bf16(
                                af, bAll[ss][1], acc[f][1], 0, 0, 0);
                        }
                    }
                }
            }
        }
        if (kt < 7) {
            WRITEA(buf ^ 1);
            bar_lds();
        }
    }
    #undef LOADST
    #undef WRITEA

    // epilogue: window-local stores (block's contiguous 512 KB of out)
    #pragma unroll
    for (int f = 0; f < NFR; ++f) {
        if (f < NF) {
            const int sp_s = __builtin_amdgcn_readfirstlane(
                (f >= F1) + (f >= F2) + (f >= F3));
            const float bv0 = bias[sp_s * NMAXD + w * 32 + lrow];
            const float bv1 = bias[sp_s * NMAXD + w * 32 + 16 + lrow];
            #pragma unroll
            for (int q = 0; q < 4; ++q) {
                const int atom = s2a[16 * f + lgr * 4 + q];
                if (atom >= 0) {
                    float* orow = out + (size_t)(g * BM + atom) * NMAXD + w * 32 + lrow;
                    orow[0]  = acc[f][0][q] + bv0;
                    orow[16] = acc[f][1][q] + bv1;
                }
            }
        }
    }
}

extern "C" void kernel_launch(void* const* d_in, const int* in_sizes, int n_in,
                              void* d_out, int out_size, void* d_ws, size_t ws_size,
                              hipStream_t stream) {
    const float* rho = (const float*)d_in[0];
    const float* W   = (const float*)d_in[1];
    const float* b   = (const float*)d_in[2];
    const int*   sym = (const int*)d_in[3];
    float* out = (float*)d_out;

    short* Wp = (short*)d_ws;   // 2 MB

    pack_w_kernel<<<(NSPE * DIM_O * NMAXD) / 256, 256, 0, stream>>>(W, Wp);
    gemm_kernel<<<NTA / BM, 1024, 0, stream>>>(rho, Wp, b, sym, out);
}

// Round 17
// 148.669 us; speedup vs baseline: 4.5666x; 4.5666x over previous
//
#include <hip/hip_runtime.h>

// Species-routed expert Linear, R17: natural-order BM=128 blocks + in-block
// species sort (<=11 fragments of 16), BN=256, 512 threads / 8 waves
// (2/SIMD -> 256-VGPR cap: acc[11][2]+bAll[4][2] fits WITHOUT spilling,
// which is what killed R16). Linear rho reads, window-local out writes,
// B granules of all 4 species register-shared per K-step (scalar select).
//   out[a] = rho[a] @ W[sym[a]] + b[sym[a]]   (NTA=65536, K=N=512, 4 species)

#define NTA   65536
#define DIM_O 512
#define NMAXD 512
#define NSPE  4
#define BM    128
#define NFR   11            // max fragments: ceil-sum bound (128+4*15)/16
#define NSLOT (NFR * 16)    // 176
#define BK    64

typedef __attribute__((ext_vector_type(4))) float  f32x4;
typedef __attribute__((ext_vector_type(8))) short  bf16x8;

__device__ __forceinline__ short f2bf(float f) {
    unsigned u = __builtin_bit_cast(unsigned, f);
    u += 0x7FFFu + ((u >> 16) & 1u);
    return (short)(u >> 16);
}

__device__ __forceinline__ void bar_lds() {
    asm volatile("s_waitcnt lgkmcnt(0)" ::: "memory");
    __builtin_amdgcn_s_barrier();
    __builtin_amdgcn_sched_barrier(0);
}

// Pack W[s][k][n] (fp32) -> bf16 MFMA-B fragment layout (proven R1-R16).
__global__ void pack_w_kernel(const float* __restrict__ W, short* __restrict__ Wp) {
    int idx = blockIdx.x * 256 + threadIdx.x;
    int j  = idx & 7;
    int l  = (idx >> 3) & 63;
    int nb = (idx >> 9) & 31;
    int kb = (idx >> 14) & 15;
    int s  = idx >> 18;
    int k = kb * 32 + (l >> 4) * 8 + j;
    int n = nb * 16 + (l & 15);
    Wp[idx] = f2bf(W[((size_t)s * DIM_O + k) * NMAXD + n]);
}

// LDS A (per BK=64 buffer): 16B granule idx = c*NSLOT + (slot ^ ((2c)&15)),
// c = k-chunk of 8 floats (0..7); XOR stays within each 16-slot fragment.
// Fragment read (slot=16f+lrow consecutive): 2-way max = free.
__global__ __launch_bounds__(512, 1)
void gemm_kernel(const float* __restrict__ rho,
                 const short* __restrict__ Wp,
                 const float* __restrict__ bias,
                 const int*  __restrict__ sym,
                 float* __restrict__ out)
{
    const int blk  = blockIdx.x;
    const int g    = blk >> 1;            // 128-atom window (siblings adjacent)
    const int ch   = blk & 1;             // N half
    const int tid  = threadIdx.x;
    const int lane = tid & 63;
    const int w    = tid >> 6;            // wave 0..7 owns cols ch*256+w*32+..
    const int lrow = lane & 15;
    const int lgr  = lane >> 4;

    __shared__ int wcnt[2][NSPE];
    __shared__ int slotOf[BM];
    __shared__ int s2a[NSLOT];
    __shared__ int Fsh[4];
    __shared__ __align__(16) short Ab[2][8 * NSLOT * 8];   // 2 x 22.5 KB

    if (tid < NSLOT) s2a[tid] = -1;

    unsigned long long ms = 0;
    int myspe = 0;
    if (tid < BM) {                       // waves 0..1 sort their 64 atoms
        myspe = sym[g * BM + tid];
        const unsigned long long m0 = __ballot(myspe == 0);
        const unsigned long long m1 = __ballot(myspe == 1);
        const unsigned long long m2 = __ballot(myspe == 2);
        const unsigned long long m3 = __ballot(myspe == 3);
        if (lane == 0) {
            wcnt[tid >> 6][0] = __popcll(m0); wcnt[tid >> 6][1] = __popcll(m1);
            wcnt[tid >> 6][2] = __popcll(m2); wcnt[tid >> 6][3] = __popcll(m3);
        }
        ms = (myspe == 0) ? m0 : (myspe == 1) ? m1 : (myspe == 2) ? m2 : m3;
    }
    __syncthreads();
    if (tid < BM) {
        int F[NSPE + 1]; F[0] = 0;
        #pragma unroll
        for (int sp = 0; sp < NSPE; ++sp)
            F[sp + 1] = F[sp] + ((wcnt[0][sp] + wcnt[1][sp] + 15) >> 4);
        int rank = (tid >= 64) ? wcnt[0][myspe] : 0;
        rank += (int)__popcll(ms & ((1ull << lane) - 1ull));
        const int slot = F[myspe] * 16 + rank;
        slotOf[tid] = slot;
        s2a[slot] = tid;
        if (tid == 0) { Fsh[0] = F[1]; Fsh[1] = F[2]; Fsh[2] = F[3]; Fsh[3] = F[4]; }
    }
    __syncthreads();

    const int F1 = Fsh[0], F2 = Fsh[1], F3 = Fsh[2], NF = Fsh[3];

    // linear staging: 4 threads/row, thread covers 16 consecutive floats;
    // 4 adjacent lanes = 256 B contiguous of one row (requests merge).
    const int srow = tid >> 2;            // natural row 0..127
    const int p    = tid & 3;
    const float* gsrc = rho + (size_t)(g * BM + srow) * DIM_O + p * 16;
    const int slotR = slotOf[srow];
    const int ca = 2 * p, cb = 2 * p + 1;
    const int ga = (ca * NSLOT + (slotR ^ ((2 * ca) & 15))) * 8;
    const int gb = (cb * NSLOT + (slotR ^ ((2 * cb) & 15))) * 8;

    f32x4 st[4];
    #define LOADST(kt)                                                      \
        { _Pragma("unroll")                                                 \
          for (int i = 0; i < 4; ++i)                                       \
              st[i] = *(const f32x4*)(gsrc + (kt) * BK + i * 4); }
    #define WRITEA(bb)                                                      \
        { bf16x8 p0, p1;                                                    \
          _Pragma("unroll")                                                 \
          for (int q = 0; q < 4; ++q) {                                     \
              p0[q] = f2bf(st[0][q]); p0[4 + q] = f2bf(st[1][q]);           \
              p1[q] = f2bf(st[2][q]); p1[4 + q] = f2bf(st[3][q]);           \
          }                                                                 \
          *(bf16x8*)&Ab[bb][ga] = p0;                                       \
          *(bf16x8*)&Ab[bb][gb] = p1; }

    f32x4 acc[NFR][2];
    #pragma unroll
    for (int f = 0; f < NFR; ++f) { acc[f][0] = (f32x4)0.0f; acc[f][1] = (f32x4)0.0f; }

    LOADST(0);
    WRITEA(0);
    __syncthreads();

    for (int kt = 0; kt < 8; ++kt) {
        const int buf = kt & 1;
        if (kt < 7) LOADST(kt + 1);       // linear next-step loads, early

        #pragma unroll
        for (int ks = 0; ks < 2; ++ks) {
            const int kb = kt * 2 + ks;
            // B granules of ALL 4 species for this wave's 32 cols, loaded once
            bf16x8 bAll[NSPE][2];
            #pragma unroll
            for (int ss = 0; ss < NSPE; ++ss)
                #pragma unroll
                for (int nf = 0; nf < 2; ++nf)
                    bAll[ss][nf] = *(const bf16x8*)
                        (Wp + ((size_t)(ss * 16 + kb) * 32
                               + (ch * 16 + w * 2 + nf)) * 512 + lane * 8);
            const int cA = ks * 4 + lgr;
            #pragma unroll
            for (int f = 0; f < NFR; ++f) {
                if (f < NF) {
                    const int sp_s = __builtin_amdgcn_readfirstlane(
                        (f >= F1) + (f >= F2) + (f >= F3));
                    const bf16x8 af = *(const bf16x8*)
                        &Ab[buf][(cA * NSLOT + ((16 * f + lrow) ^ ((2 * cA) & 15))) * 8];
                    #pragma unroll
                    for (int ss = 0; ss < NSPE; ++ss) {
                        if (ss == sp_s) {   // scalar branch, exactly one taken
                            acc[f][0] = __builtin_amdgcn_mfma_f32_16x16x32_bf16(
                                af, bAll[ss][0], acc[f][0], 0, 0, 0);
                            acc[f][1] = __builtin_amdgcn_mfma_f32_16x16x32_bf16(
                                af, bAll[ss][1], acc[f][1], 0, 0, 0);
                        }
                    }
                }
            }
        }
        if (kt < 7) {
            WRITEA(buf ^ 1);
            bar_lds();
        }
    }
    #undef LOADST
    #undef WRITEA

    // epilogue: window-local stores (block's contiguous 256 KB of out)
    #pragma unroll
    for (int f = 0; f < NFR; ++f) {
        if (f < NF) {
            const int sp_s = __builtin_amdgcn_readfirstlane(
                (f >= F1) + (f >= F2) + (f >= F3));
            const float bv0 = bias[sp_s * NMAXD + ch * 256 + w * 32 + lrow];
            const float bv1 = bias[sp_s * NMAXD + ch * 256 + w * 32 + 16 + lrow];
            #pragma unroll
            for (int q = 0; q < 4; ++q) {
                const int atom = s2a[16 * f + lgr * 4 + q];
                if (atom >= 0) {
                    float* orow = out + (size_t)(g * BM + atom) * NMAXD
                                + ch * 256 + w * 32 + lrow;
                    orow[0]  = acc[f][0][q] + bv0;
                    orow[16] = acc[f][1][q] + bv1;
                }
            }
        }
    }
}

extern "C" void kernel_launch(void* const* d_in, const int* in_sizes, int n_in,
                              void* d_out, int out_size, void* d_ws, size_t ws_size,
                              hipStream_t stream) {
    const float* rho = (const float*)d_in[0];
    const float* W   = (const float*)d_in[1];
    const float* b   = (const float*)d_in[2];
    const int*   sym = (const int*)d_in[3];
    float* out = (float*)d_out;

    short* Wp = (short*)d_ws;   // 2 MB

    pack_w_kernel<<<(NSPE * DIM_O * NMAXD) / 256, 256, 0, stream>>>(W, Wp);
    gemm_kernel<<<2 * (NTA / BM), 512, 0, stream>>>(rho, Wp, b, sym, out);
}

// Round 18
// 121.703 us; speedup vs baseline: 5.5785x; 1.2216x over previous
//
#include <hip/hip_runtime.h>

// Species-routed expert Linear as a bucketed grouped GEMM.
//   out[a] = rho[a] @ W[sym[a]] + b[sym[a]]   (NTA=65536, K=N=512, 4 species)
// FINAL (= R13, best measured: 121.7 us total, gemm ~100 us, absmax 0.031):
// full A-tile prologue gather -> 64KB LDS (0-conflict XOR layout),
// barrier-free K-loop (L2-resident packed-bf16 B + MFMA), LDS-transpose
// epilogue with 1KB-contiguous NON-TEMPORAL row stores. 17 rounds of
// ablation showed the remaining time is the species-scattered row gather
// (~2.9 TB/s) + scattered row stores (~2.2 TB/s) — the address pattern given
// by the problem's routing, not the schedule.

#define NTA   65536
#define DIM_O 512
#define NMAXD 512
#define NSPE  4
#define BM    64
#define BK    64

typedef __attribute__((ext_vector_type(4))) float  f32x4;
typedef __attribute__((ext_vector_type(8))) short  bf16x8;
typedef __attribute__((ext_vector_type(4))) short  bf16x4;

__device__ __forceinline__ short f2bf(float f) {
    unsigned u = __builtin_bit_cast(unsigned, f);
    u += 0x7FFFu + ((u >> 16) & 1u);
    return (short)(u >> 16);
}

// LDS-visibility barrier that does NOT drain vmcnt
__device__ __forceinline__ void bar_lds() {
    asm volatile("s_waitcnt lgkmcnt(0)" ::: "memory");
    __builtin_amdgcn_s_barrier();
    __builtin_amdgcn_sched_barrier(0);
}

__global__ void build_lists_kernel(const int* __restrict__ sym,
                                   int* __restrict__ counts,
                                   int* __restrict__ lists) {
    int i = blockIdx.x * 256 + threadIdx.x;
    int s = sym[i];
    int lane = threadIdx.x & 63;
    #pragma unroll
    for (int spe = 0; spe < NSPE; ++spe) {
        unsigned long long m = __ballot(s == spe);
        if (m == 0ull) continue;
        int leader = __ffsll(m) - 1;
        int base = 0;
        if (lane == leader) base = atomicAdd(&counts[spe], __popcll(m));
        base = __shfl(base, leader);
        if (s == spe) {
            int pos = __popcll(m & ((1ull << lane) - 1ull));
            lists[spe * NTA + base + pos] = i;
        }
    }
}

// Pack W[s][k][n] (fp32) -> bf16 MFMA-B fragment layout; also zeroes counts
// (launched BEFORE build_lists on the same stream).
__global__ void pack_w_kernel(const float* __restrict__ W, short* __restrict__ Wp,
                              int* __restrict__ counts) {
    if (blockIdx.x == 0 && threadIdx.x < NSPE) counts[threadIdx.x] = 0;
    int idx = blockIdx.x * 256 + threadIdx.x;
    int j  = idx & 7;
    int l  = (idx >> 3) & 63;
    int nb = (idx >> 9) & 31;
    int kb = (idx >> 14) & 15;
    int s  = idx >> 18;
    int k = kb * 32 + (l >> 4) * 8 + j;
    int n = nb * 16 + (l & 15);
    Wp[idx] = f2bf(W[((size_t)s * DIM_O + k) * NMAXD + n]);
}

// LDS A layout (full K): 16B slot = c*64 + (row ^ ((c&3)<<1)),
// c = k-chunk of 8 floats (0..63). Measured 0 conflicts (R6/R7).
__global__ __launch_bounds__(512, 4)
void gemm_kernel(const float* __restrict__ rho,
                 const short* __restrict__ Wp,
                 const float* __restrict__ bias,
                 const int*  __restrict__ counts,
                 const int*  __restrict__ lists,
                 float* __restrict__ out)
{
    const int s   = blockIdx.x & 3;
    const int mb  = blockIdx.x >> 2;
    const int cnt = counts[s];
    const int row0 = mb * BM;
    if (row0 >= cnt) return;
    int rows_here = cnt - row0; if (rows_here > BM) rows_here = BM;

    __shared__ int aidx[BM];
    __shared__ __align__(16) short Abuf[64 * 64 * 8];   // 64 KB: A tile, then O-transpose

    const int tid  = threadIdx.x;
    const int lane = tid & 63;
    const int w    = tid >> 6;            // wave 0..7 owns cols [w*64, w*64+64)
    const int lrow = lane & 15;
    const int lgr  = lane >> 4;

    if (tid < BM)
        aidx[tid] = lists[s * NTA + row0 + ((tid < rows_here) ? tid : 0)];
    __syncthreads();

    // ---- prologue: gather the WHOLE A tile (once), convert, stage to LDS ----
    {
        const int srow  = tid >> 3;
        const int scol8 = tid & 7;
        const float* gsrc = rho + (size_t)aidx[srow] * DIM_O + scol8 * 4;
        const int c0   = scol8 >> 1;
        const int roww = srow ^ ((c0 & 3) << 1);
        const int dof  = (scol8 & 1) * 4;

        f32x4 v[16];
        #pragma unroll
        for (int r = 0; r < 16; ++r)
            v[r] = *(const f32x4*)(gsrc + r * 32);
        #pragma unroll
        for (int r = 0; r < 16; ++r) {
            bf16x4 a;
            #pragma unroll
            for (int q = 0; q < 4; ++q) a[q] = f2bf(v[r][q]);
            *(bf16x4*)&Abuf[((r * 4 + c0) * 64 + roww) * 8 + dof] = a;
        }
    }
    __syncthreads();

    // ---- barrier-free K-loop: read-only LDS + L2-resident B + MFMA ----
    const short* wbase = Wp + ((size_t)s * 512 + w * 4) * 512 + lane * 8;

    f32x4 acc[4][4];
    #pragma unroll
    for (int m = 0; m < 4; ++m)
        #pragma unroll
        for (int n = 0; n < 4; ++n) acc[m][n] = (f32x4)0.0f;

    #pragma unroll
    for (int kt = 0; kt < 8; ++kt) {
        bf16x8 bfr[2][4];
        #pragma unroll
        for (int ks = 0; ks < 2; ++ks)
            #pragma unroll
            for (int nf = 0; nf < 4; ++nf)
                bfr[ks][nf] = *(const bf16x8*)
                    (wbase + (size_t)((kt * 2 + ks) * 32 + nf) * 512);
        #pragma unroll
        for (int ks = 0; ks < 2; ++ks) {
            #pragma unroll
            for (int mf = 0; mf < 4; ++mf) {
                const int c = kt * 8 + ks * 4 + lgr;
                const int r = (mf * 16 + lrow) ^ ((lgr & 3) << 1);
                const bf16x8 afrag = *(const bf16x8*)&Abuf[(c * 64 + r) * 8];
                #pragma unroll
                for (int nf = 0; nf < 4; ++nf)
                    acc[mf][nf] = __builtin_amdgcn_mfma_f32_16x16x32_bf16(
                        afrag, bfr[ks][nf], acc[mf][nf], 0, 0, 0);
            }
        }
    }

    // ---- epilogue: LDS transpose -> contiguous 1KB NON-TEMPORAL stores ----
    float bv[4];
    #pragma unroll
    for (int nf = 0; nf < 4; ++nf)
        bv[nf] = bias[s * NMAXD + w * 64 + nf * 16 + lrow];

    float* Obuf = (float*)Abuf;   // 32 rows x 512 f32 per pass = 64 KB
    bar_lds();                    // all A-tile LDS reads done before overwrite

    #pragma unroll
    for (int p = 0; p < 2; ++p) {
        // write phase: acc rows [p*32, p*32+32); col-XOR by row -> 2-way max
        #pragma unroll
        for (int m2 = 0; m2 < 2; ++m2) {
            const int mf = p * 2 + m2;
            #pragma unroll
            for (int q = 0; q < 4; ++q) {
                const int rl = m2 * 16 + lgr * 4 + q;          // 0..31
                const int sw = ((rl >> 2) & 3) << 4;
                #pragma unroll
                for (int nf = 0; nf < 4; ++nf) {
                    const int col = w * 64 + nf * 16 + lrow;
                    Obuf[rl * 512 + (col ^ sw)] = acc[mf][nf][q] + bv[nf];
                }
            }
        }
        bar_lds();
        // read+store phase: wave w stores rows [w*4, w*4+4); 1KB contiguous/instr
        #pragma unroll
        for (int rr = 0; rr < 4; ++rr) {
            const int rl = w * 4 + rr;
            const int gr = p * 32 + rl;
            const int sw = ((rl >> 2) & 3) << 4;
            if (gr < rows_here) {
                float* orow = out + (size_t)aidx[gr] * NMAXD;
                #pragma unroll
                for (int h = 0; h < 2; ++h) {
                    const int cd = h * 256 + lane * 4;
                    f32x4 v = *(const f32x4*)&Obuf[rl * 512 + (cd ^ sw)];
                    __builtin_nontemporal_store(v, (f32x4*)&orow[cd]);
                }
            }
        }
        if (p == 0) bar_lds();
    }
}

extern "C" void kernel_launch(void* const* d_in, const int* in_sizes, int n_in,
                              void* d_out, int out_size, void* d_ws, size_t ws_size,
                              hipStream_t stream) {
    const float* rho = (const float*)d_in[0];
    const float* W   = (const float*)d_in[1];
    const float* b   = (const float*)d_in[2];
    const int*   sym = (const int*)d_in[3];
    float* out = (float*)d_out;

    int*   counts = (int*)d_ws;
    int*   lists  = (int*)((char*)d_ws + 1024);
    short* Wp     = (short*)((char*)d_ws + 1024 + (size_t)NSPE * NTA * 4);

    pack_w_kernel<<<(NSPE * DIM_O * NMAXD) / 256, 256, 0, stream>>>(W, Wp, counts);
    build_lists_kernel<<<NTA / 256, 256, 0, stream>>>(sym, counts, lists);
    gemm_kernel<<<NSPE * (NTA / BM), 512, 0, stream>>>(rho, Wp, b, counts, lists, out);
}